// Round 1
// 819.908 us; speedup vs baseline: 1.0578x; 1.0578x over previous
//
#include <hip/hip_runtime.h>
#include <hip/hip_bf16.h>
#include <stdint.h>

typedef _Float16 f16;
typedef __attribute__((ext_vector_type(8))) _Float16 half8;
typedef __attribute__((ext_vector_type(4))) float f32x4;

typedef __attribute__((address_space(1))) void gvoid_t;
typedef __attribute__((address_space(3))) void lvoid_t;

// HBM -> LDS DMA, 16 B per lane. LDS dest is wave-uniform base + lane*16.
__device__ __forceinline__ void dma16(const void* g, void* l) {
    __builtin_amdgcn_global_load_lds((gvoid_t*)g, (lvoid_t*)l, 16, 0, 0);
}

// ---------------------------------------------------------------------------
// P1: transpose + cast x [8,4096,256] f32 -> xT [8,256,4096] f16
// grid (64, 4, 8), block 256
// ---------------------------------------------------------------------------
__global__ void __launch_bounds__(256) transpose_x_kernel(
    const float* __restrict__ x, f16* __restrict__ xT)
{
    __shared__ __align__(16) f16 tile[64][72];
    int b  = blockIdx.z;
    int m0 = blockIdx.x * 64;
    int d0 = blockIdx.y * 64;
    const float* xb = x + (size_t)b * 4096 * 256;
    f16* xTb = xT + (size_t)b * 256 * 4096;
    int tid = threadIdx.x;
    int c4 = tid & 15;
    int rb = tid >> 4;
#pragma unroll
    for (int p = 0; p < 4; ++p) {
        int row = p * 16 + rb;
        float4 v = *(const float4*)(xb + (size_t)(m0 + row) * 256 + d0 + c4 * 4);
        tile[c4 * 4 + 0][row] = (f16)v.x;
        tile[c4 * 4 + 1][row] = (f16)v.y;
        tile[c4 * 4 + 2][row] = (f16)v.z;
        tile[c4 * 4 + 3][row] = (f16)v.w;
    }
    __syncthreads();
    int mseg = tid & 7;
    int db = tid >> 3;
#pragma unroll
    for (int p = 0; p < 2; ++p) {
        int dd = p * 32 + db;
        uint4 val = *(const uint4*)&tile[dd][mseg * 8];
        *(uint4*)(xTb + (size_t)(d0 + dd) * 4096 + m0 + mseg * 8) = val;
    }
}

// ---------------------------------------------------------------------------
// P2: weight transposes to n-major f16
// ---------------------------------------------------------------------------
__global__ void __launch_bounds__(256) prep_weights_kernel(
    const float* __restrict__ W1, const float* __restrict__ W2,
    f16* __restrict__ W1T, f16* __restrict__ W2T)
{
    int idx = blockIdx.x * 256 + threadIdx.x;
    if (idx < 131072) {
        int n = idx >> 8;
        int k = idx & 255;
        W1T[idx] = (f16)W1[k * 512 + n];
    } else {
        int j = idx - 131072;
        int d = j >> 9;
        int hh = j & 511;
        W2T[j] = (f16)W2[hh * 256 + d];
    }
}

// ---------------------------------------------------------------------------
// K1: h = (1+eps)*x + adj @ x   (per batch), f16 MFMA, fp32 accum.
// NEW STRUCTURE:
//   grid 256 blocks (1 per CU), 512 threads (8 waves, 4m x 2n, wave tile 32x128)
//   BM=128, BN=256 (full d), BK=32, 128 K-iters.
//   Batch-per-XCD: batch = bid & 7  ->  each XCD's L2 holds exactly one xT slab.
//   4 LDS buffers, prefetch depth 2, counted vmcnt (tile t+1/t+2 stay in
//   flight across the barrier), ONE raw s_barrier per iter.
//   Race-freedom: DMA(t+2) overwrites buf[(t+2)&3] which holds tile t-2;
//   every wave's compute(t-2) precedes barrier(t-1), and the DMA issue is
//   after barrier(t-1) in program order -> safe with 4 buffers.
// A kept fp32 in LDS (DMA can't convert); cvt at frag read.
// XOR-swizzled unpadded layouts -> DMA-compatible AND ~conflict-free reads.
// ---------------------------------------------------------------------------
__device__ __forceinline__ void bmm_dma_tile(
    const float* adjb, const f16* xTb, float* AsBuf, f16* BsBuf,
    int kk, int wid, int lane)
{
    // A tile: 128 rows x 32 f32 (16 KB) = 16 chunks of 8 rows; wave w: w, w+8
    int a_rr = lane >> 3, a_sl = lane & 7;
#pragma unroll
    for (int c = 0; c < 2; ++c) {
        int chunk = wid + c * 8;
        int r = chunk * 8 + a_rr;
        int colg = a_sl ^ ((r & 7) ^ ((r >> 3) & 1));   // swizzle slot of 4 floats
        dma16(adjb + (size_t)r * 4096 + kk + colg * 4, AsBuf + chunk * 256);
    }
    // B tile: 256 rows x 32 f16 (16 KB) = 16 chunks of 16 rows; wave w: w, w+8
    int b_rr = lane >> 2, b_sl = lane & 3;
#pragma unroll
    for (int c = 0; c < 2; ++c) {
        int chunk = wid + c * 8;
        int r = chunk * 16 + b_rr;
        int colg = b_sl ^ ((r & 3) ^ ((r >> 2) & 3));   // swizzle slot of 8 f16
        dma16(xTb + (size_t)r * 4096 + kk + colg * 8, BsBuf + chunk * 512);
    }
}

__global__ void __launch_bounds__(512) bmm_kernel(
    const float* __restrict__ adj, const f16* __restrict__ xT,
    const float* __restrict__ x, const float* __restrict__ eps,
    f16* __restrict__ h)
{
    __shared__ __align__(16) float As[4][128 * 32];   // 4 x 16 KB
    __shared__ __align__(16) f16  Bs[4][256 * 32];    // 4 x 16 KB   (128 KB total)

    const int lin = blockIdx.x;
    const int b   = lin & 7;            // batch -> XCD affinity (round-robin by 8)
    const int m0  = (lin >> 3) * 128;
    const int tid = threadIdx.x;
    const int lane = tid & 63, wid = tid >> 6;
    const int wm = (wid & 3) * 32;      // 4 wave-rows of 32
    const int wn = (wid >> 2) * 128;    // 2 wave-cols of 128
    const int l15 = lane & 15, lg = lane >> 4;

    const float* adjb = adj + (size_t)b * 4096 * 4096 + (size_t)m0 * 4096;
    const f16*   xTb  = xT  + (size_t)b * 256 * 4096;

    f32x4 acc[2][8];
#pragma unroll
    for (int i = 0; i < 2; ++i)
#pragma unroll
        for (int j = 0; j < 8; ++j) { f32x4 z = {0.f, 0.f, 0.f, 0.f}; acc[i][j] = z; }

    // prologue: DMA tiles 0 and 1 (depth-2 pipeline)
    bmm_dma_tile(adjb, xTb, As[0], Bs[0], 0, wid, lane);
    bmm_dma_tile(adjb, xTb, As[1], Bs[1], 32, wid, lane);

    // frag-read swizzle factors (depend only on l15; tile bases are x16 aligned)
    const int sA = (l15 & 7) ^ (l15 >> 3);
    const int sB = (l15 & 3) ^ ((l15 >> 2) & 3);

    for (int it = 0; it < 128; ++it) {
        // issue tile it+2 (4 vmem instrs per wave: A,A,B,B)
        if (it + 2 < 128)
            bmm_dma_tile(adjb, xTb, As[(it + 2) & 3], Bs[(it + 2) & 3],
                         (it + 2) * 32, wid, lane);

        // counted wait: tile `it`'s 4 loads done; it+1/it+2 stay in flight
        if (it < 126)       asm volatile("s_waitcnt vmcnt(8)" ::: "memory");
        else if (it == 126) asm volatile("s_waitcnt vmcnt(4)" ::: "memory");
        else                asm volatile("s_waitcnt vmcnt(0)" ::: "memory");
        __builtin_amdgcn_s_barrier();            // all waves: tile `it` landed
        asm volatile("" ::: "memory");           // pin LDS reads below barrier

        const float* Ab = As[it & 3];
        const f16*  Bb  = Bs[it & 3];
        half8 af[2];
#pragma unroll
        for (int mt = 0; mt < 2; ++mt) {
            int R = wm + mt * 16 + l15;
            int p0 = (2 * lg) ^ sA;
            f32x4 a0 = *(const f32x4*)&Ab[R * 32 + p0 * 4];
            f32x4 a1 = *(const f32x4*)&Ab[R * 32 + (p0 ^ 1) * 4];
            half8 t;
            t[0] = (f16)a0.x; t[1] = (f16)a0.y; t[2] = (f16)a0.z; t[3] = (f16)a0.w;
            t[4] = (f16)a1.x; t[5] = (f16)a1.y; t[6] = (f16)a1.z; t[7] = (f16)a1.w;
            af[mt] = t;
        }
        half8 bfr[8];
        const int slotB = lg ^ sB;
#pragma unroll
        for (int nt = 0; nt < 8; ++nt) {
            int C = wn + nt * 16 + l15;
            bfr[nt] = *(const half8*)&Bb[C * 32 + slotB * 8];
        }
#pragma unroll
        for (int mt = 0; mt < 2; ++mt)
#pragma unroll
            for (int nt = 0; nt < 8; ++nt)
                acc[mt][nt] = __builtin_amdgcn_mfma_f32_16x16x32_f16(af[mt], bfr[nt], acc[mt][nt], 0, 0, 0);
    }

    // epilogue: h = (1+eps)*x + acc   (C/D: col = l15, row = lg*4 + i)
    float scale = 1.0f + eps[0];
    const float* xb = x + (size_t)b * 4096 * 256;
    f16* hb = h + (size_t)b * 4096 * 256;
#pragma unroll
    for (int mt = 0; mt < 2; ++mt) {
#pragma unroll
        for (int i = 0; i < 4; ++i) {
            int row = m0 + wm + mt * 16 + lg * 4 + i;
#pragma unroll
            for (int nt = 0; nt < 8; ++nt) {
                int col = wn + nt * 16 + l15;
                float hv = scale * xb[(size_t)row * 256 + col] + acc[mt][nt][i];
                hb[(size_t)row * 256 + col] = (f16)hv;
            }
        }
    }
}

// ---------------------------------------------------------------------------
// K2/K3: C = act(A @ BT^T + bias). A [M,K] f16, BT [N,K] f16.
// BM=128, BN=128, BK=32, 4 waves (2x2), wave tile 64x64.
// One-barrier DMA double-buffer structure (unchanged).
// ---------------------------------------------------------------------------
__device__ __forceinline__ void mlp_dma_tile(
    const f16* Am, const f16* Bn, f16* AsBuf, f16* BsBuf,
    int kk, int K, int wid, int lane)
{
    // each tile: 128 rows x 32 f16 (8 KB) = 8 chunks of 16 rows; wave w: w, w+4
    int rr = lane >> 2, sl = lane & 3;
#pragma unroll
    for (int c = 0; c < 2; ++c) {
        int chunk = wid + c * 4;
        int r = chunk * 16 + rr;
        int colg = sl ^ ((r & 3) ^ ((r >> 2) & 3));
        dma16(Am + (size_t)r * K + kk + colg * 8, AsBuf + chunk * 512);
        dma16(Bn + (size_t)r * K + kk + colg * 8, BsBuf + chunk * 512);
    }
}

template <int K, bool RELU, bool OUTF32>
__global__ void __launch_bounds__(256) mlp_kernel(
    const f16* __restrict__ A, const f16* __restrict__ BT,
    const float* __restrict__ bias, void* __restrict__ outv, int Ntot)
{
    __shared__ __align__(16) f16 As[2][128 * 32];   // 2 x 8 KB
    __shared__ __align__(16) f16 Bs[2][128 * 32];

    const int m0 = blockIdx.x * 128;
    const int n0 = blockIdx.y * 128;
    const int tid = threadIdx.x;
    const int lane = tid & 63, wid = tid >> 6;
    const int wm = (wid & 1) * 64;
    const int wn = (wid >> 1) * 64;
    const int l15 = lane & 15, lg = lane >> 4;

    const f16* Am = A  + (size_t)m0 * K;
    const f16* Bn = BT + (size_t)n0 * K;

    f32x4 acc[4][4];
#pragma unroll
    for (int i = 0; i < 4; ++i)
#pragma unroll
        for (int j = 0; j < 4; ++j) { f32x4 z = {0.f, 0.f, 0.f, 0.f}; acc[i][j] = z; }

    mlp_dma_tile(Am, Bn, As[0], Bs[0], 0, K, wid, lane);

    const int sf = (l15 & 3) ^ ((l15 >> 2) & 3);
    const int slot = lg ^ sf;
    const int NIT = K / 32;

    for (int it = 0; it < NIT; ++it) {
        const int buf = it & 1;
        __syncthreads();
        if (it + 1 < NIT)
            mlp_dma_tile(Am, Bn, As[buf ^ 1], Bs[buf ^ 1], (it + 1) * 32, K, wid, lane);

        half8 af[4], bf[4];
#pragma unroll
        for (int mt = 0; mt < 4; ++mt) {
            int R = wm + mt * 16 + l15;
            af[mt] = *(const half8*)&As[buf][R * 32 + slot * 8];
        }
#pragma unroll
        for (int nt = 0; nt < 4; ++nt) {
            int C = wn + nt * 16 + l15;
            bf[nt] = *(const half8*)&Bs[buf][C * 32 + slot * 8];
        }
#pragma unroll
        for (int mt = 0; mt < 4; ++mt)
#pragma unroll
            for (int nt = 0; nt < 4; ++nt)
                acc[mt][nt] = __builtin_amdgcn_mfma_f32_16x16x32_f16(af[mt], bf[nt], acc[mt][nt], 0, 0, 0);
    }

#pragma unroll
    for (int mt = 0; mt < 4; ++mt) {
#pragma unroll
        for (int i = 0; i < 4; ++i) {
            int row = m0 + wm + mt * 16 + lg * 4 + i;
#pragma unroll
            for (int nt = 0; nt < 4; ++nt) {
                int col = n0 + wn + nt * 16 + l15;
                float v = acc[mt][nt][i] + bias[col];
                if (RELU) v = v > 0.f ? v : 0.f;
                if (OUTF32)
                    ((float*)outv)[(size_t)row * Ntot + col] = v;
                else
                    ((f16*)outv)[(size_t)row * Ntot + col] = (f16)v;
            }
        }
    }
}

// ---------------------------------------------------------------------------
// launch
// ---------------------------------------------------------------------------
extern "C" void kernel_launch(void* const* d_in, const int* in_sizes, int n_in,
                              void* d_out, int out_size, void* d_ws, size_t ws_size,
                              hipStream_t stream) {
    (void)in_sizes; (void)n_in; (void)out_size; (void)ws_size;
    const float* x   = (const float*)d_in[0];
    const float* adj = (const float*)d_in[1];
    const float* eps = (const float*)d_in[2];
    const float* W1  = (const float*)d_in[3];
    const float* b1  = (const float*)d_in[4];
    const float* W2  = (const float*)d_in[5];
    const float* b2  = (const float*)d_in[6];
    float* out = (float*)d_out;

    char* ws = (char*)d_ws;
    f16* h_f16   = (f16*)(ws);                       // 16 MiB
    f16* xT      = (f16*)(ws + (16u << 20));         // 16 MiB (later reused by hidden)
    f16* hidden  = (f16*)(ws + (16u << 20));         // 32 MiB
    f16* W1T     = (f16*)(ws + (48u << 20));
    f16* W2T     = (f16*)(ws + (48u << 20) + 131072u * 2u * 2u);

    transpose_x_kernel<<<dim3(64, 4, 8), dim3(256), 0, stream>>>(x, xT);
    prep_weights_kernel<<<dim3(1024), dim3(256), 0, stream>>>(W1, W2, W1T, W2T);
    bmm_kernel<<<dim3(256), dim3(512), 0, stream>>>(adj, xT, x, eps, h_f16);
    mlp_kernel<256, true, false><<<dim3(256, 4), dim3(256), 0, stream>>>(h_f16, W1T, b1, (void*)hidden, 512);
    mlp_kernel<512, false, true><<<dim3(256, 2), dim3(256), 0, stream>>>(hidden, W2T, b2, (void*)out, 256);
}